// Round 9
// baseline (48.731 us; speedup 1.0000x reference)
//
#include <hip/hip_runtime.h>
#include <cstdint>

static constexpr int Bc = 32, Tc = 128, Fc = 32, Hc = 4, HDc = 16, RKc = 16;
static constexpr int Nc = Tc * Fc;  // 4096
static constexpr int WS36 = 36;     // row-major [*][32] padded stride
static constexpr int TS = 132;      // transposed [32][128] padded stride

__device__ __forceinline__ uint32_t rotl32(uint32_t v, int r) {
  return (v << r) | (v >> (32 - r));
}

__device__ __forceinline__ void threefry2x32(uint32_t k0, uint32_t k1,
                                             uint32_t& x0, uint32_t& x1) {
  uint32_t k2 = k0 ^ k1 ^ 0x1BD11BDAu;
  x0 += k0; x1 += k1;
#define TF_R(r) { x0 += x1; x1 = rotl32(x1, (r)); x1 ^= x0; }
  TF_R(13) TF_R(15) TF_R(26) TF_R(6)
  x0 += k1; x1 += k2 + 1u;
  TF_R(17) TF_R(29) TF_R(16) TF_R(24)
  x0 += k2; x1 += k0 + 2u;
  TF_R(13) TF_R(15) TF_R(26) TF_R(6)
  x0 += k0; x1 += k1 + 3u;
  TF_R(17) TF_R(29) TF_R(16) TF_R(24)
  x0 += k1; x1 += k2 + 4u;
  TF_R(13) TF_R(15) TF_R(26) TF_R(6)
  x0 += k2; x1 += k0 + 5u;
#undef TF_R
}

// XLA ErfInv32; __logf (v_log_f32) — rel err ~1e-6, harmless for v0/sn.
__device__ __forceinline__ float erfinv_f32(float x) {
  float w = -__logf((1.0f - x) * (1.0f + x));
  float p;
  if (w < 5.0f) {
    w -= 2.5f;
    p = 2.81022636e-08f;
    p = fmaf(p, w, 3.43273939e-07f);
    p = fmaf(p, w, -3.5233877e-06f);
    p = fmaf(p, w, -4.39150654e-06f);
    p = fmaf(p, w, 0.00021858087f);
    p = fmaf(p, w, -0.00125372503f);
    p = fmaf(p, w, -0.00417768164f);
    p = fmaf(p, w, 0.246640727f);
    p = fmaf(p, w, 1.50140941f);
  } else {
    w = sqrtf(w) - 3.0f;
    p = -0.000200214257f;
    p = fmaf(p, w, 0.000100950558f);
    p = fmaf(p, w, 0.00134934322f);
    p = fmaf(p, w, -0.00367342844f);
    p = fmaf(p, w, 0.00573950773f);
    p = fmaf(p, w, -0.0076224613f);
    p = fmaf(p, w, 0.00943887047f);
    p = fmaf(p, w, 1.00167406f);
    p = fmaf(p, w, 2.83297682f);
  }
  return p * x;
}

__device__ __forceinline__ float jax_normal_from_bits(uint32_t bits) {
  const float lo = -0.99999994f;
  float f = __uint_as_float((bits >> 9) | 0x3f800000u) - 1.0f;
  float u = fmaxf(lo, f * 2.0f + lo);
  return 1.41421354f * erfinv_f32(u);
}

// ---------------------------------------------------------------------------
// K1: scores + row softmax + threshold + dense ta + per-row CSR.
// grid (h, chunk=8 of 16 rows), 512 threads. (unchanged from R8 — proven)
// ---------------------------------------------------------------------------
__global__ __launch_bounds__(512)
void score_kernel(const float* __restrict__ x, const float* __restrict__ weight,
                  const float* __restrict__ tqg, const float* __restrict__ tkg,
                  float* __restrict__ ws_ta, float* __restrict__ ws_rs,
                  int* __restrict__ ws_rowcnt, int* __restrict__ ws_cols,
                  float* __restrict__ ws_vals) {
  const int h = blockIdx.x, chunk = blockIdx.y;
  const int tid = (int)threadIdx.x;
  __shared__ float kS[Bc][Tc];
  __shared__ float qS[Bc][16];
  __shared__ float wqv[Fc], wkv[Fc];

  if (tid < Fc) {
    const float* W0 = weight + h * (Fc * HDc);
    float aq = 0.f, ak = 0.f;
    for (int d = 0; d < HDc; ++d) {
      float w0 = W0[tid * HDc + d];
      aq += w0 * tqg[h * HDc + d];
      ak += w0 * tkg[h * HDc + d];
    }
    wqv[tid] = aq; wkv[tid] = ak;
  }
  __syncthreads();

  for (int i = tid; i < Bc * Tc; i += 512) {
    const float4* xr = (const float4*)(x + (size_t)i * Fc);
    float ak = 0.f;
#pragma unroll
    for (int j = 0; j < 8; ++j) {
      float4 v = xr[j];
      ak += v.x * wkv[4*j] + v.y * wkv[4*j+1] + v.z * wkv[4*j+2] + v.w * wkv[4*j+3];
    }
    kS[i >> 7][i & 127] = ak;
  }
  {
    int b = tid >> 4, tt = tid & 15;
    const float4* xr = (const float4*)(x + ((size_t)b * Tc + 16 * chunk + tt) * Fc);
    float aq = 0.f;
#pragma unroll
    for (int j = 0; j < 8; ++j) {
      float4 v = xr[j];
      aq += v.x * wqv[4*j] + v.y * wqv[4*j+1] + v.z * wqv[4*j+2] + v.w * wqv[4*j+3];
    }
    qS[b][tt] = aq;
  }
  __syncthreads();

  const int t1l = tid >> 5, t2q = tid & 31;
  const int gt1 = 16 * chunk + t1l;
  float acc[4] = {};
  for (int b = 0; b < Bc; ++b) {
    float q = qS[b][t1l];
    float4 k4 = *(const float4*)&kS[b][4 * t2q];
    float kv[4] = {k4.x, k4.y, k4.z, k4.w};
#pragma unroll
    for (int j = 0; j < 4; ++j) {
      float s = q + kv[j];
      acc[j] += fmaxf(s, 0.2f * s);
    }
  }
#pragma unroll
  for (int j = 0; j < 4; ++j) acc[j] *= (1.0f / 32.0f);

  float m = fmaxf(fmaxf(acc[0], acc[1]), fmaxf(acc[2], acc[3]));
  for (int o = 16; o > 0; o >>= 1) m = fmaxf(m, __shfl_xor(m, o, 32));
  float e[4], se = 0.f;
#pragma unroll
  for (int j = 0; j < 4; ++j) { e[j] = expf(acc[j] - m); se += e[j]; }
  for (int o = 16; o > 0; o >>= 1) se += __shfl_xor(se, o, 32);
  float p[4]; int keep[4]; int cnt = 0; float rs = 0.f;
#pragma unroll
  for (int j = 0; j < 4; ++j) {
    float pv = e[j] / se;
    int col = 4 * t2q + j;
    int k = (pv > 0.01f) && (col != gt1);
    p[j] = k ? pv : 0.f;
    keep[j] = k;
    cnt += k;
    rs += p[j];
  }
  for (int o = 16; o > 0; o >>= 1) rs += __shfl_xor(rs, o, 32);

  float* tar = ws_ta + (size_t)h * (Tc * Tc) + (size_t)gt1 * Tc + 4 * t2q;
  *(float4*)tar = make_float4(p[0], p[1], p[2], p[3]);

  int ci = cnt;
  for (int o = 1; o < 32; o <<= 1) {
    int u = __shfl_up(ci, o, 32);
    if (t2q >= o) ci += u;
  }
  int excl = ci - cnt;
  int total = __shfl(ci, 31, 32);
  if (t2q == 0) {
    ws_rowcnt[h * Tc + gt1] = total;
    ws_rs[h * Tc + gt1] = rs;
  }
  int off = gt1 * Tc + excl;
#pragma unroll
  for (int j = 0; j < 4; ++j) {
    if (keep[j]) {
      ws_cols[h * (Tc * Tc) + off] = 4 * t2q + j;
      ws_vals[h * (Tc * Tc) + off] = p[j];
      ++off;
    }
  }
}

// ---------------------------------------------------------------------------
// K2: fused head+conv, 1024 threads (16 waves -> 4/SIMD). grid (b,h) = 128.
// pi map: rows {t, t+64} (t = tid&63), cols f0 = 2*(tid>>6) (wave-uniform).
// G map: t2 = tid&127, f = 4*(tid>>7).  out map: t2, hd = 2*(tid>>7).
// x loaded to registers at entry (latency hidden under fa+PRNG+pi).
// ---------------------------------------------------------------------------
__global__ __launch_bounds__(1024, 1)
void fused_kernel(const float* __restrict__ x, const float* __restrict__ weight,
                  const float* __restrict__ bias, const float* __restrict__ ffg,
                  const float* __restrict__ ws_ta, const float* __restrict__ ws_rs,
                  const int* __restrict__ ws_rowcnt, const int* __restrict__ ws_cols,
                  const float* __restrict__ ws_vals, float* __restrict__ out) {
  const int b = blockIdx.x, h = blockIdx.y;
  const int tid = (int)threadIdx.x;
  const int lane = tid & 63, wv = tid >> 6;   // wv 0..15

  __shared__ __align__(16) float bufRow[Tc * WS36]; // pi w -> Zs -> GT
  __shared__ __align__(16) float bufT[Fc * TS];     // pi wT -> ZT
  __shared__ __align__(16) float XT[Fc * TS];
  __shared__ __align__(16) float faS[Fc * WS36];    // fa[f1][f2]
  __shared__ __align__(16) float faTS[Fc * WS36];   // faT[f2][f1]
  __shared__ __align__(16) float W0s[Fc * HDc];
  __shared__ __align__(16) float W1s[Fc * HDc];
  __shared__ float rsT[Tc], rsF[Fc], red[16];
  __shared__ int rcS[Tc], flagS;

  // ---- early x load: 1 float4/thread, consumed after pi (hides HBM latency)
  const float* xb = x + (size_t)b * Nc;
  const int xrow = tid >> 3, xc4 = tid & 7;
  float4 xv4 = *(const float4*)&xb[xrow * Fc + 4 * xc4];

  if (tid < Tc) {
    rsT[tid] = ws_rs[h * Tc + tid];
    rcS[tid] = ws_rowcnt[h * Tc + tid];
  }
  if (tid < Fc * HDc) {
    W0s[tid] = weight[h * (Fc * HDc) + tid];
    W1s[tid] = weight[(Hc + h) * (Fc * HDc) + tid];
  }

  // fa = threshold(softmax(leaky_relu(U V^T), axis=1)); one cell/thread
  {
    const float* U = ffg + h * (2 * Fc * RKc);
    const float* V = U + Fc * RKc;
    int f1 = tid >> 5, f2 = tid & 31;
    float acc = 0.f;
    for (int r = 0; r < RKc; ++r) acc += U[f1 * RKc + r] * V[f2 * RKc + r];
    float val = fmaxf(acc, 0.2f * acc);
    float m = val;
    for (int o = 16; o > 0; o >>= 1) m = fmaxf(m, __shfl_xor(m, o, 32));
    float e = expf(val - m), se = e;
    for (int o = 16; o > 0; o >>= 1) se += __shfl_xor(se, o, 32);
    float pv = e / se;
    pv = (pv > 0.01f && f1 != f2) ? pv : 0.f;
    faS[f1 * WS36 + f2] = pv;
    faTS[f2 * WS36 + f1] = pv;
    float rsum = pv;
    for (int o = 16; o > 0; o >>= 1) rsum += __shfl_xor(rsum, o, 32);
    if (f2 == 0) rsF[f1] = rsum;
  }
  __syncthreads();  // rsT/rcS/W/fa/rsF visible

  if (tid < 64) {
    int nz = (rcS[tid] != 0) || (rcS[tid + 64] != 0);
    unsigned long long bal = __ballot(nz);
    if (tid == 0) flagS = (bal != 0ull) ? 1 : 0;
  }

  // ---- power iteration: rows {t, t+64}, cols {f0, f0+1} (f0 wave-uniform)
  const int t = tid & 63, f0 = 2 * (tid >> 6);
  float v_reg[2][2], s_reg[2][2], nv[2][2];
#pragma unroll
  for (int r = 0; r < 2; ++r) {
    float rrow = rsT[t + 64 * r];
#pragma unroll
    for (int j = 0; j < 2; ++j)
      s_reg[r][j] = 1.0f / sqrtf(rrow + rsF[f0 + j] + 1.0f + 1e-10f);
  }
  {
    uint32_t fk0 = 0u, fk1 = (uint32_t)h;
    threefry2x32(0u, 42u, fk0, fk1);
#pragma unroll
    for (int j = 0; j < 2; ++j) {
      int l = t * Fc + f0 + j;  // < 2048 (t < 64)
      uint32_t c0 = (uint32_t)l, c1 = (uint32_t)(l + 2048);
      threefry2x32(fk0, fk1, c0, c1);
      v_reg[0][j] = jax_normal_from_bits(c0);   // (t, f)
      v_reg[1][j] = jax_normal_from_bits(c1);   // (t+64, f)
    }
  }
#pragma unroll
  for (int r = 0; r < 2; ++r) {
    int row = t + 64 * r;
    float2 w = make_float2(s_reg[r][0] * v_reg[r][0], s_reg[r][1] * v_reg[r][1]);
    *(float2*)&bufRow[row * WS36 + f0] = w;
    bufT[f0 * TS + row] = w.x;
    bufT[(f0 + 1) * TS + row] = w.y;
  }
  __syncthreads();  // w visible; flagS visible

  const int csrBase = h * (Tc * Tc);
  float snv = 1.0f;
  for (int it = 0; it < 4; ++it) {
    float acc[2][2] = {};
    if (flagS) {  // M1 sparse CSR (skipped when ta == 0)
#pragma unroll
      for (int r = 0; r < 2; ++r) {
        int row = t + 64 * r;
        int bse = csrBase + row * Tc, cnt = rcS[row];
        for (int e = 0; e < cnt; ++e) {
          int col = ws_cols[bse + e];
          float val = ws_vals[bse + e];
          float2 w2 = *(const float2*)&bufRow[col * WS36 + f0];
          acc[r][0] += val * w2.x; acc[r][1] += val * w2.y;
        }
      }
    }
    // M2: sum_f2 fa[f][f2] * w[row][f2]
    for (int f2 = 0; f2 < Fc; ++f2) {
      float2 fav = *(const float2*)&faTS[f2 * WS36 + f0];  // broadcast
      float w0 = bufT[f2 * TS + t];                        // lane-consecutive
      float w1 = bufT[f2 * TS + t + 64];
      acc[0][0] += w0 * fav.x; acc[0][1] += w0 * fav.y;
      acc[1][0] += w1 * fav.x; acc[1][1] += w1 * fav.y;
    }
    float partv = 0.f;
#pragma unroll
    for (int r = 0; r < 2; ++r)
#pragma unroll
      for (int j = 0; j < 2; ++j) {
        float a = acc[r][j] + s_reg[r][j] * v_reg[r][j];  // + identity
        float nvv = v_reg[r][j] - s_reg[r][j] * a;        // (Lv)
        nv[r][j] = nvv;
        partv += (it < 3) ? nvv * nvv : v_reg[r][j] * nvv;
      }
    for (int o = 32; o > 0; o >>= 1) partv += __shfl_down(partv, o, 64);
    if (lane == 0) red[wv] = partv;
    __syncthreads();
    float total = 0.f;
#pragma unroll
    for (int i2 = 0; i2 < 16; ++i2) total += red[i2];  // redundant, broadcast
    if (it < 3) {
      float inv = 1.0f / (sqrtf(total) + 1e-10f);
#pragma unroll
      for (int r = 0; r < 2; ++r) {
        int row = t + 64 * r;
#pragma unroll
        for (int j = 0; j < 2; ++j) v_reg[r][j] = nv[r][j] * inv;
        float2 w = make_float2(s_reg[r][0] * v_reg[r][0], s_reg[r][1] * v_reg[r][1]);
        *(float2*)&bufRow[row * WS36 + f0] = w;
        bufT[f0 * TS + row] = w.x;
        bufT[(f0 + 1) * TS + row] = w.y;
      }
      __syncthreads();
    } else {
      snv = fmaxf(fabsf(total), 1.0f);
    }
  }
  const float csn = 2.0f / snv;
  const float cm1 = csn - 1.0f;

  // ---- stage x (registers -> LDS): Zs(=bufRow), ZT(=bufT), XT
  {
    float rrow = rsT[xrow];
    float s0 = 1.0f / sqrtf(rrow + rsF[4 * xc4 + 0] + 1.0f + 1e-10f);
    float s1 = 1.0f / sqrtf(rrow + rsF[4 * xc4 + 1] + 1.0f + 1e-10f);
    float s2 = 1.0f / sqrtf(rrow + rsF[4 * xc4 + 2] + 1.0f + 1e-10f);
    float s3 = 1.0f / sqrtf(rrow + rsF[4 * xc4 + 3] + 1.0f + 1e-10f);
    float4 zv = make_float4(xv4.x * s0, xv4.y * s1, xv4.z * s2, xv4.w * s3);
    *(float4*)&bufRow[xrow * WS36 + 4 * xc4] = zv;
    XT[(4 * xc4 + 0) * TS + xrow] = xv4.x; bufT[(4 * xc4 + 0) * TS + xrow] = zv.x;
    XT[(4 * xc4 + 1) * TS + xrow] = xv4.y; bufT[(4 * xc4 + 1) * TS + xrow] = zv.y;
    XT[(4 * xc4 + 2) * TS + xrow] = xv4.z; bufT[(4 * xc4 + 2) * TS + xrow] = zv.z;
    XT[(4 * xc4 + 3) * TS + xrow] = xv4.w; bufT[(4 * xc4 + 3) * TS + xrow] = zv.w;
  }
  __syncthreads();

  // ---- G phase: t2 = tid&127, f = fgc..fgc+4 (fgc wave-uniform); G -> regs
  const int t2 = tid & 127, fgc = 4 * (tid >> 7);
  float greg[4];
  {
    float acc[4] = {};
    if (flagS) {  // rare path: dense ta from global (L2-resident)
      const float* taG = ws_ta + (size_t)h * (Tc * Tc);
      for (int k = 0; k < Tc; ++k) {
        float ta0 = taG[k * Tc + t2];                            // coalesced
        float4 z0 = *(const float4*)&bufRow[k * WS36 + fgc];     // broadcast
        acc[0] += ta0 * z0.x; acc[1] += ta0 * z0.y;
        acc[2] += ta0 * z0.z; acc[3] += ta0 * z0.w;
      }
    }
    for (int f2 = 0; f2 < Fc; ++f2) {
      float4 fa0 = *(const float4*)&faS[f2 * WS36 + fgc];  // broadcast
      float zt0 = bufT[f2 * TS + t2];                      // lane-consecutive
      acc[0] += zt0 * fa0.x; acc[1] += zt0 * fa0.y;
      acc[2] += zt0 * fa0.z; acc[3] += zt0 * fa0.w;
    }
    float rrow = rsT[t2];
#pragma unroll
    for (int j = 0; j < 4; ++j) {
      int f = fgc + j;
      float xvv = XT[f * TS + t2];
      float zvv = bufT[f * TS + t2];
      float sv = 1.0f / sqrtf(rrow + rsF[f] + 1.0f + 1e-10f);
      greg[j] = cm1 * xvv - csn * sv * (acc[j] + zvv);
    }
  }
  __syncthreads();  // all reads of bufRow (Zs) complete
#pragma unroll
  for (int j = 0; j < 4; ++j) bufRow[(fgc + j) * TS + t2] = greg[j];  // GT
  __syncthreads();

  // ---- out GEMM: t2 lanes, hd = {hd0, hd0+1} (hd0 wave-uniform)
  {
    const int hd0 = 2 * (tid >> 7);
    float2 acc2 = make_float2(0.f, 0.f);
    for (int f = 0; f < Fc; ++f) {
      float2 w0 = *(const float2*)&W0s[f * HDc + hd0];  // broadcast
      float2 w1 = *(const float2*)&W1s[f * HDc + hd0];  // broadcast
      float xvv = XT[f * TS + t2];
      float gvv = bufRow[f * TS + t2];
      acc2.x += xvv * w0.x + gvv * w1.x;
      acc2.y += xvv * w0.y + gvv * w1.y;
    }
    float2 bv = *(const float2*)&bias[h * HDc + hd0];
    float2 o2 = make_float2(acc2.x + bv.x, acc2.y + bv.y);
    *(float2*)&out[((size_t)b * Tc + t2) * (Hc * HDc) + h * HDc + hd0] = o2;
  }
}

extern "C" void kernel_launch(void* const* d_in, const int* in_sizes, int n_in,
                              void* d_out, int out_size, void* d_ws, size_t ws_size,
                              hipStream_t stream) {
  const float* x      = (const float*)d_in[0];
  const float* weight = (const float*)d_in[1];
  const float* bias   = (const float*)d_in[2];
  const float* tqg    = (const float*)d_in[3];
  const float* tkg    = (const float*)d_in[4];
  const float* ffg    = (const float*)d_in[5];
  float* out = (float*)d_out;

  float* ws = (float*)d_ws;
  float* ws_ta     = ws;                    // 4*16384 = 65536
  float* ws_rs     = ws + 65536;            // 512
  int*   ws_rowcnt = (int*)(ws + 66048);    // 512
  int*   ws_cols   = (int*)(ws + 66560);    // 65536
  float* ws_vals   = ws + 132096;           // 65536

  score_kernel<<<dim3(Hc, 8), dim3(512), 0, stream>>>(
      x, weight, tqg, tkg, ws_ta, ws_rs, ws_rowcnt, ws_cols, ws_vals);
  fused_kernel<<<dim3(Bc, Hc), dim3(1024), 0, stream>>>(
      x, weight, bias, ffg, ws_ta, ws_rs, ws_rowcnt, ws_cols, ws_vals, out);
}